// Round 1
// baseline (321.058 us; speedup 1.0000x reference)
//
#include <hip/hip_runtime.h>

// Problem constants (setup_inputs: B=2, N=256, D=256, H=8, LEN=516)
#define NPAIR 131072   // B*N*N
#define NDIM  256      // D
#define NH    8        // heads
#define NN    256      // N (k-dimension for topk / ind)
#define NROWS 512      // B*N rows for topk
#define LEN   516      // 2*D + 4
#define EPSV  1e-8f

__device__ __forceinline__ float dot4(float4 a, float4 b) {
    return fmaf(a.x, b.x, fmaf(a.y, b.y, fmaf(a.z, b.z, a.w * b.w)));
}

// DPP add step: x += dpp_shifted(x); invalid lanes contribute old=0.
#define DPP_ADD(x, ctrl)                                                        \
    x += __int_as_float(__builtin_amdgcn_update_dpp(                            \
        0, __float_as_int(x), (ctrl), 0xf, 0xf, false))

// Full wave64 sum via DPP (VALU only, no LDS pipe), result uniform.
__device__ __forceinline__ float wave_sum(float x) {
    DPP_ADD(x, 0x111);  // row_shr:1
    DPP_ADD(x, 0x112);  // row_shr:2
    DPP_ADD(x, 0x114);  // row_shr:4
    DPP_ADD(x, 0x118);  // row_shr:8  -> lane 15 of each row holds row sum
    DPP_ADD(x, 0x142);  // row_bcast:15 -> lane31 = r0+r1, lane63 = r2+r3
    DPP_ADD(x, 0x143);  // row_bcast:31 -> lane63 = total
    return __int_as_float(
        __builtin_amdgcn_readlane(__float_as_int(x), 63));
}

// Kernel 1: one wave per (b,q,k) pair. Lanes cover D (4 floats each).
// Computes: scores[p] = relu(cos(q,k)) and out[p*8+h] = sigmoid(lin_h)*roi[p].
__global__ __launch_bounds__(256) void fused_main(
    const float* __restrict__ Q, const float* __restrict__ K,
    const float* __restrict__ SQ, const float* __restrict__ SK,
    const float* __restrict__ ROI, const float* __restrict__ W,
    const float* __restrict__ Bb, float* __restrict__ out,
    float* __restrict__ scores)
{
    const int lane = threadIdx.x & 63;
    const int h = lane & 7;
    const int nwaves = (gridDim.x * blockDim.x) >> 6;
    const int wave = (blockIdx.x * blockDim.x + threadIdx.x) >> 6;

    // Cache W fragments in VGPRs: lane holds W[h][4*lane..4*lane+3] (q half)
    // and W[h][256+4*lane..] (k half) for all 8 heads -> 64 VGPRs.
    float4 wq[NH], wk[NH];
#pragma unroll
    for (int i = 0; i < NH; i++) {
        wq[i] = *(const float4*)(W + i * LEN + lane * 4);
        wk[i] = *(const float4*)(W + i * LEN + 256 + lane * 4);
    }
    // Spatial tail + bias for this lane's head (lane&7).
    const float4 wt = *(const float4*)(W + h * LEN + 512);
    const float bh = Bb[h];

    for (int p0 = wave; p0 < NPAIR; p0 += nwaves) {
        const int p = __builtin_amdgcn_readfirstlane(p0);
        const float4 qv = *(const float4*)(Q + (size_t)p * NDIM + lane * 4);
        const float4 kv = *(const float4*)(K + (size_t)p * NDIM + lane * 4);

        float aqq = dot4(qv, qv);
        float akk = dot4(kv, kv);
        float aqk = dot4(qv, kv);
        float sh[2 * NH];
#pragma unroll
        for (int i = 0; i < NH; i++) {
            sh[i]      = dot4(qv, wq[i]);
            sh[NH + i] = dot4(kv, wk[i]);
        }

        const float qq = wave_sum(aqq);
        const float kk = wave_sum(akk);
        const float qk = wave_sum(aqk);

        // Per-lane head value: lane&7 selects its head's projection sum.
        float x = 0.0f;
#pragma unroll
        for (int i = 0; i < NH; i++) {
            const float si = wave_sum(sh[i]) + wave_sum(sh[NH + i]);
            x = (h == i) ? si : x;
        }

        // Cosine score, relu'd.
        float qn = fmaxf(sqrtf(qq), EPSV);
        float kn = fmaxf(sqrtf(kk), EPSV);
        float sc = fmaxf(qk / (qn * kn), 0.0f);
        if (lane == 0) scores[p] = sc;

        // Spatial terms + bias, sigmoid, roi mask.
        const float sq0 = SQ[2 * p], sq1 = SQ[2 * p + 1];
        const float sk0 = SK[2 * p], sk1 = SK[2 * p + 1];
        x += sq0 * wt.x + sq1 * wt.y + sk0 * wt.z + sk1 * wt.w + bh;
        float y = 1.0f / (1.0f + __expf(-x));
        y *= ROI[p];
        if (lane < NH) out[(size_t)p * NH + lane] = y;
    }
}

// Kernel 2: zero the indicator (ws is poisoned 0xAA before each launch).
__global__ void zero_ind(float* __restrict__ ind) {
    ind[threadIdx.x] = 0.0f;
}

// Kernel 3: per (b,q) row, extract top-k indices (stable: ties -> lower
// index) and mark ind[idx] = 1.0. One wave per row.
__global__ __launch_bounds__(64) void topk_kernel(
    const float* __restrict__ scores, float* __restrict__ ind,
    const int* __restrict__ node_num)
{
    const int row = blockIdx.x;
    const int lane = threadIdx.x;
    const float4 v4 = *(const float4*)(scores + row * NN + lane * 4);
    float v[4] = {v4.x, v4.y, v4.z, v4.w};

    int Kk = node_num[0];
    if (Kk > NN) Kk = NN;
    for (int t = 0; t < Kk; t++) {
        // lane-local argmax (ties -> lower index via strict >)
        float mv = v[0];
        int mi = lane * 4;
#pragma unroll
        for (int j = 1; j < 4; j++) {
            if (v[j] > mv) { mv = v[j]; mi = lane * 4 + j; }
        }
        // wave argmax, ties -> lower index
        for (int off = 32; off > 0; off >>= 1) {
            const float ov = __shfl_xor(mv, off, 64);
            const int   oi = __shfl_xor(mi, off, 64);
            if (ov > mv || (ov == mv && oi < mi)) { mv = ov; mi = oi; }
        }
        if (lane == 0) ind[mi] = 1.0f;       // idempotent concurrent 1.0 store
        if ((mi >> 2) == lane) v[mi & 3] = -1.0f;  // remove (scores >= 0)
    }
}

// Kernel 4: out *= ind[k]; float4 over out (element e: k = (e/8)%256).
__global__ __launch_bounds__(256) void apply_ind_kernel(
    float* __restrict__ out, const float* __restrict__ ind)
{
    const int i = blockIdx.x * blockDim.x + threadIdx.x;  // float4 index
    float4 v = ((float4*)out)[i];
    const float m = ind[(i >> 1) & (NN - 1)];
    v.x *= m; v.y *= m; v.z *= m; v.w *= m;
    ((float4*)out)[i] = v;
}

extern "C" void kernel_launch(void* const* d_in, const int* in_sizes, int n_in,
                              void* d_out, int out_size, void* d_ws, size_t ws_size,
                              hipStream_t stream)
{
    const float* Q   = (const float*)d_in[0];
    const float* K   = (const float*)d_in[1];
    const float* SQ  = (const float*)d_in[2];
    const float* SK  = (const float*)d_in[3];
    const float* ROI = (const float*)d_in[4];
    const float* W   = (const float*)d_in[5];
    const float* Bb  = (const float*)d_in[6];
    const int* node_num = (const int*)d_in[7];

    float* out = (float*)d_out;
    float* scores = (float*)d_ws;          // NPAIR floats (512 KB)
    float* ind = scores + NPAIR;           // NN floats

    fused_main<<<1024, 256, 0, stream>>>(Q, K, SQ, SK, ROI, W, Bb, out, scores);
    zero_ind<<<1, 256, 0, stream>>>(ind);
    topk_kernel<<<NROWS, 64, 0, stream>>>(scores, ind, node_num);
    apply_ind_kernel<<<out_size / 4 / 256, 256, 0, stream>>>(out, ind);
}